// Round 14
// baseline (119.168 us; speedup 1.0000x reference)
//
#include <hip/hip_runtime.h>

#define LN 4096
#define DN 150
#define NT 10          // d padded to 10 x 16 tiles

// legacy (TR=1) geometry
#define KSPLIT 4
#define KQ 1024        // k per block
#define NSS 4          // super-steps of 256 k

// h_out (k_gemm_a) geometry
#define KS0 16
#define KQ0 (LN / KS0)     // 256 k per block

typedef __attribute__((ext_vector_type(8))) short bf16x8;
typedef __attribute__((ext_vector_type(4))) float f32x4;

// round-to-nearest-even fp32 -> bf16 (finite inputs only)
__device__ __forceinline__ unsigned int f2bf(float f) {
    unsigned int u = __builtin_bit_cast(unsigned int, f);
    u = (u + 0x7FFFu + ((u >> 16) & 1u)) >> 16;
    return u & 0xFFFFu;
}

__global__ __launch_bounds__(256) void k_zero(f32x4* __restrict__ p, int n4) {
    int i = blockIdx.x * 256 + threadIdx.x;
    if (i < n4) p[i] = (f32x4){0.f, 0.f, 0.f, 0.f};
}

// h [4096][150] f32  ->  Ht [160][4096] bf16 (rows 150..159 zero)
__global__ __launch_bounds__(256) void k_transpose(const float* __restrict__ h,
                                                   unsigned short* __restrict__ Ht) {
    __shared__ float S[64][33];
    const int i0 = blockIdx.x * 64;
    const int d0 = blockIdx.y * 32;
    const int tid = threadIdx.x;
    for (int t = tid; t < 64 * 32; t += 256) {
        int ii = t >> 5, dd = t & 31;
        int d = d0 + dd;
        S[ii][dd] = (d < DN) ? h[(size_t)(i0 + ii) * DN + d] : 0.0f;
    }
    __syncthreads();
    for (int t = tid; t < 32 * 64; t += 256) {
        int dd = t >> 6, ii = t & 63;
        Ht[(size_t)(d0 + dd) * LN + i0 + ii] = (unsigned short)f2bf(S[ii][dd]);
    }
}

// out h_in = sum of 4 pIn partials; out h_out = sum of 16 pOut partials.
__global__ __launch_bounds__(256) void k_reduce(const float* __restrict__ pIn,
                                                const float* __restrict__ pOut,
                                                float* __restrict__ out, int n4) {
    int i = blockIdx.x * 256 + threadIdx.x;
    if (i >= n4) return;
    const f32x4* a = reinterpret_cast<const f32x4*>(pIn);
    const f32x4* b = reinterpret_cast<const f32x4*>(pOut);
    f32x4 s0 = a[i], s1 = b[i];
    #pragma unroll
    for (int k = 1; k < KSPLIT; ++k) s0 += a[(size_t)k * n4 + i];
    #pragma unroll
    for (int k = 1; k < KS0; ++k)    s1 += b[(size_t)k * n4 + i];
    reinterpret_cast<f32x4*>(out)[i] = s0;             // h_in
    reinterpret_cast<f32x4*>(out)[n4 + i] = s1;        // h_out
}

// ---------------- h_out gemm: barrier-free phase-split, 4 blocks/CU ----------------
// part[by][m0+row][d] = sum_{k in 256-k window} bf16(adj[m][k][0]+adj[m][k][1]) * Ht[d][k]
// Wave w owns rows w*16..w*16+15 exclusively (stage AND compute) -> no __syncthreads.
// LDS: [64 rows][128 u32 = 256 bf16] = 32 KB; 16B-chunk (c ^ (row&7)) holds global chunk c.
__global__ __launch_bounds__(256, 4) void k_gemm_a(const float* __restrict__ adj,
                                                   const unsigned short* __restrict__ Ht,
                                                   float* __restrict__ part) {
    __shared__ unsigned int Abf[64 * 128];   // 32 KB
    const int tid  = threadIdx.x;
    const int lane = tid & 63;
    const int w    = tid >> 6;
    const int r16  = lane & 15;
    const int g    = lane >> 4;
    const int m0 = blockIdx.x * 64;
    const int kq = blockIdx.y * KQ0;

    // ---- phase 1: wave-local stream + convert (no barriers) ----
    // Wave's 16 rows x 2KB raw each; lane l covers u32-cols {l, 64+l} of each 128-u32 row.
    #pragma unroll
    for (int t4 = 0; t4 < 4; ++t4) {       // 4 batches of 4 rows (8 KB/wave in flight)
        f32x4 v[8];
        #pragma unroll
        for (int t = 0; t < 4; ++t) {
            const int r = w * 16 + t4 * 4 + t;
            const float* rowp = adj + ((size_t)(m0 + r) * LN + kq) * 2;
            v[t * 2]     = *reinterpret_cast<const f32x4*>(rowp + lane * 4);
            v[t * 2 + 1] = *reinterpret_cast<const f32x4*>(rowp + 256 + lane * 4);
        }
        #pragma unroll
        for (int t = 0; t < 4; ++t) {
            const int r = w * 16 + t4 * 4 + t;
            #pragma unroll
            for (int q = 0; q < 2; ++q) {
                f32x4 x = v[t * 2 + q];
                unsigned int u = f2bf(x.x + x.y) | (f2bf(x.z + x.w) << 16);
                int cg = q * 64 + lane;                       // global u32 col (0..127)
                int chunk = (cg >> 2) ^ (r & 7);              // swizzled 16B chunk
                Abf[r * 128 + (chunk << 2) + (cg & 3)] = u;
            }
        }
    }
    // per-wave lgkmcnt ordering suffices: rows are wave-private

    // ---- phase 2: MFMA sweep (8 k-steps of 32) ----
    f32x4 acc[NT];
    #pragma unroll
    for (int n = 0; n < NT; ++n) acc[n] = (f32x4){0.f, 0.f, 0.f, 0.f};
    const int rA = w * 16 + r16;
    const unsigned int* abase = &Abf[rA * 128];
    #pragma unroll
    for (int ks = 0; ks < 8; ++ks) {
        bf16x8 a = *reinterpret_cast<const bf16x8*>(abase + (((ks * 4 + g) ^ (r16 & 7)) << 2));
        const int k = kq + ks * 32 + g * 8;
        bf16x8 B[NT];
        #pragma unroll
        for (int n = 0; n < NT; ++n)
            B[n] = *reinterpret_cast<const bf16x8*>(Ht + (size_t)(n * 16 + r16) * LN + k);
        #pragma unroll
        for (int n = 0; n < NT; ++n)
            acc[n] = __builtin_amdgcn_mfma_f32_16x16x32_bf16(a, B[n], acc[n], 0, 0, 0);
    }

    // epilogue: direct partial store (wave owns its 16 rows)
    float* dst = part + (size_t)blockIdx.y * (LN * DN);
    #pragma unroll
    for (int n = 0; n < NT; ++n) {
        #pragma unroll
        for (int q = 0; q < 4; ++q) {
            int row = w * 16 + g * 4 + q;   // C: col=lane&15, row=(lane>>4)*4+q
            int col = n * 16 + r16;
            if (col < DN) dst[(size_t)(m0 + row) * DN + col] = acc[n][q];
        }
    }
}

// ---------------- legacy reg-staged gemm (TR=1 main path + fallback) ----------------
template <int TR>
__global__ __launch_bounds__(256, 2) void k_gemm(const float* __restrict__ adj,
                                                 const unsigned short* __restrict__ Ht,
                                                 float* __restrict__ part,
                                                 float* __restrict__ out) {
    __shared__ unsigned short At[2][32 * 256];
    __shared__ float red[32][160];
    const int tid  = threadIdx.x;
    const int lane = tid & 63;
    const int wave = tid >> 6;
    const int r16  = lane & 15;
    const int g    = lane >> 4;
    const int m0 = blockIdx.x * 32;
    const int kq = blockIdx.y * KQ;

    f32x4 acc[2][NT];
    #pragma unroll
    for (int mt = 0; mt < 2; ++mt)
        #pragma unroll
        for (int n = 0; n < NT; ++n) acc[mt][n] = (f32x4){0.f, 0.f, 0.f, 0.f};

    f32x4 sv[16];

    auto stage_load = [&](int ss) {
        if (TR == 0) {
            const int row = tid >> 7;
            const int kk  = tid & 127;
            #pragma unroll
            for (int rr = 0; rr < 16; ++rr) {
                int rowr = rr * 2 + row;
                sv[rr] = *reinterpret_cast<const f32x4*>(
                    adj + ((size_t)(m0 + rowr) * LN + kq + ss * 256 + 2 * kk) * 2);
            }
        } else {
            const int iof = tid >> 4;
            const int jp  = tid & 15;
            #pragma unroll
            for (int rr = 0; rr < 16; ++rr) {
                int il = rr * 16 + iof;
                sv[rr] = *reinterpret_cast<const f32x4*>(
                    adj + ((size_t)(kq + ss * 256 + il) * LN + m0 + jp * 2) * 2);
            }
        }
    };
    auto stage_write = [&](int buf) {
        if (TR == 0) {
            const int row = tid >> 7;
            const int kk  = tid & 127;
            #pragma unroll
            for (int rr = 0; rr < 16; ++rr) {
                int rowr = rr * 2 + row;
                unsigned int u = f2bf(sv[rr].x + sv[rr].y) | (f2bf(sv[rr].z + sv[rr].w) << 16);
                *reinterpret_cast<unsigned int*>(
                    &At[buf][rowr * 256 + ((2 * kk) ^ ((rowr & 15) << 3))]) = u;
            }
        } else {
            const int iof = tid >> 4;
            const int jA  = (tid & 15) * 2, jB = jA + 1;
            #pragma unroll
            for (int rr = 0; rr < 16; ++rr) {
                int k = rr * 16 + iof;
                At[buf][jA * 256 + (k ^ ((jA & 15) << 3))] = (unsigned short)f2bf(sv[rr].x + sv[rr].y);
                At[buf][jB * 256 + (k ^ ((jB & 15) << 3))] = (unsigned short)f2bf(sv[rr].z + sv[rr].w);
            }
        }
    };
    auto frag = [&](int buf, int mt, int s) {
        int row  = mt * 16 + r16;
        int kloc = wave * 64 + s * 32 + g * 8;
        return *reinterpret_cast<const bf16x8*>(&At[buf][row * 256 + (kloc ^ (r16 << 3))]);
    };
    auto loadB = [&](bf16x8 (&bb)[NT], int ss, int s) {
        int k = kq + ss * 256 + wave * 64 + s * 32 + g * 8;
        #pragma unroll
        for (int n = 0; n < NT; ++n)
            bb[n] = *reinterpret_cast<const bf16x8*>(Ht + (size_t)(n * 16 + r16) * LN + k);
    };

    stage_load(0);
    stage_write(0);
    __syncthreads();
    for (int ss = 0; ss < NSS; ++ss) {
        const int buf = ss & 1;
        if (ss + 1 < NSS) stage_load(ss + 1);
        #pragma unroll
        for (int s = 0; s < 2; ++s) {
            bf16x8 B[NT];
            loadB(B, ss, s);
            bf16x8 a0 = frag(buf, 0, s);
            bf16x8 a1 = frag(buf, 1, s);
            #pragma unroll
            for (int n = 0; n < NT; ++n) {
                acc[0][n] = __builtin_amdgcn_mfma_f32_16x16x32_bf16(a0, B[n], acc[0][n], 0, 0, 0);
                acc[1][n] = __builtin_amdgcn_mfma_f32_16x16x32_bf16(a1, B[n], acc[1][n], 0, 0, 0);
            }
        }
        __syncthreads();
        if (ss + 1 < NSS) stage_write(buf ^ 1);
        __syncthreads();
    }

    for (int w4 = 0; w4 < 4; ++w4) {
        if (wave == w4) {
            #pragma unroll
            for (int mt = 0; mt < 2; ++mt)
                #pragma unroll
                for (int n = 0; n < NT; ++n)
                    #pragma unroll
                    for (int q = 0; q < 4; ++q) {
                        int row = mt * 16 + g * 4 + q;
                        if (w4 == 0) red[row][n * 16 + r16]  = acc[mt][n][q];
                        else         red[row][n * 16 + r16] += acc[mt][n][q];
                    }
        }
        __syncthreads();
    }
    if (part) {
        float* dst = part + (size_t)blockIdx.y * (LN * DN);
        for (int t2 = tid; t2 < 32 * DN; t2 += 256) {
            int row = t2 / DN, col = t2 % DN;
            dst[(size_t)(m0 + row) * DN + col] = red[row][col];
        }
    } else {
        for (int t2 = tid; t2 < 32 * DN; t2 += 256) {
            int row = t2 / DN, col = t2 % DN;
            atomicAdd(&out[(size_t)(m0 + row) * DN + col], red[row][col]);
        }
    }
}

extern "C" void kernel_launch(void* const* d_in, const int* in_sizes, int n_in,
                              void* d_out, int out_size, void* d_ws, size_t ws_size,
                              hipStream_t stream) {
    const float* adj = (const float*)d_in[0];
    const float* h   = (const float*)d_in[1];
    float* out = (float*)d_out;
    char* ws = (char*)d_ws;

    unsigned short* Ht = (unsigned short*)ws;                      // 1.31 MB @ 0
    const size_t offPin  = 2u << 20;                               // h_in partials (4x)
    const size_t offPout = offPin + (size_t)KSPLIT * LN * DN * 4;  // h_out partials (16x)
    const size_t need    = offPout + (size_t)KS0 * LN * DN * 4;    // ~51 MB

    k_transpose<<<dim3(64, 5), 256, 0, stream>>>(h, Ht);

    if (ws_size >= need) {
        float* pIn  = (float*)(ws + offPin);
        float* pOut = (float*)(ws + offPout);
        k_gemm_a<<<dim3(64, KS0), 256, 0, stream>>>(adj, Ht, pOut);                // h_out
        k_gemm<1><<<dim3(128, KSPLIT), 256, 0, stream>>>(adj, Ht, pIn, nullptr);   // h_in
        const int n4 = (LN * DN) / 4;
        k_reduce<<<(n4 + 255) / 256, 256, 0, stream>>>(pIn, pOut, out, n4);
    } else {
        const int n4 = out_size / 4;
        k_zero<<<(n4 + 255) / 256, 256, 0, stream>>>((f32x4*)out, n4);
        k_gemm<0><<<dim3(128, KSPLIT), 256, 0, stream>>>(adj, Ht, nullptr, out + (size_t)LN * DN);
        k_gemm<1><<<dim3(128, KSPLIT), 256, 0, stream>>>(adj, Ht, nullptr, out);
    }
}

// Round 15
// 113.182 us; speedup vs baseline: 1.0529x; 1.0529x over previous
//
#include <hip/hip_runtime.h>

#define LN 4096
#define DN 150
#define NT 10          // d padded to 10 x 16 tiles
#define NTB 5          // N-tiles per h_out gemm block (grid.y=2 covers 160 cols)
#define NPADB 80
#define KSPLIT 4
#define KQ 1024        // k per h_in block
#define NSS 4          // super-steps of 256 k

typedef __attribute__((ext_vector_type(8))) short bf16x8;
typedef __attribute__((ext_vector_type(4))) float f32x4;

// round-to-nearest-even fp32 -> bf16 (finite inputs only)
__device__ __forceinline__ unsigned int f2bf(float f) {
    unsigned int u = __builtin_bit_cast(unsigned int, f);
    u = (u + 0x7FFFu + ((u >> 16) & 1u)) >> 16;
    return u & 0xFFFFu;
}

__global__ __launch_bounds__(256) void k_zero(f32x4* __restrict__ p, int n4) {
    int i = blockIdx.x * 256 + threadIdx.x;
    if (i < n4) p[i] = (f32x4){0.f, 0.f, 0.f, 0.f};
}

// h [4096][150] f32  ->  Ht [160][4096] bf16 (rows 150..159 zero)
__global__ __launch_bounds__(256) void k_transpose(const float* __restrict__ h,
                                                   unsigned short* __restrict__ Ht) {
    __shared__ float S[64][33];
    const int i0 = blockIdx.x * 64;
    const int d0 = blockIdx.y * 32;
    const int tid = threadIdx.x;
    for (int t = tid; t < 64 * 32; t += 256) {
        int ii = t >> 5, dd = t & 31;
        int d = d0 + dd;
        S[ii][dd] = (d < DN) ? h[(size_t)(i0 + ii) * DN + d] : 0.0f;
    }
    __syncthreads();
    for (int t = tid; t < 32 * 64; t += 256) {
        int dd = t >> 6, ii = t & 63;
        Ht[(size_t)(d0 + dd) * LN + i0 + ii] = (unsigned short)f2bf(S[ii][dd]);
    }
}

// PURE stream: Abf[i*LN+j] = bf16(adj[(i*LN+j)*2] + adj[(i*LN+j)*2+1]).
// 8192 blocks x 256 threads x 8 outputs = 16.78M, exact cover. No LDS, no barriers.
__global__ __launch_bounds__(256) void k_conv(const float* __restrict__ adj,
                                              unsigned short* __restrict__ Abf) {
    const size_t i = ((size_t)blockIdx.x * 256 + threadIdx.x) * 8;
    const f32x4* src = reinterpret_cast<const f32x4*>(adj + i * 2);
    f32x4 v0 = src[0], v1 = src[1], v2 = src[2], v3 = src[3];
    bf16x8 o;
    o[0] = (short)f2bf(v0.x + v0.y); o[1] = (short)f2bf(v0.z + v0.w);
    o[2] = (short)f2bf(v1.x + v1.y); o[3] = (short)f2bf(v1.z + v1.w);
    o[4] = (short)f2bf(v2.x + v2.y); o[5] = (short)f2bf(v2.z + v2.w);
    o[6] = (short)f2bf(v3.x + v3.y); o[7] = (short)f2bf(v3.z + v3.w);
    *reinterpret_cast<bf16x8*>(Abf + i) = o;
}

// h_in: out[i] = sum of 4 pIn partials (f32x4 granularity).
__global__ __launch_bounds__(256) void k_reduce_in(const float* __restrict__ pIn,
                                                   float* __restrict__ out, int n4) {
    int i = blockIdx.x * 256 + threadIdx.x;
    if (i >= n4) return;
    const f32x4* a = reinterpret_cast<const f32x4*>(pIn);
    f32x4 s = a[i];
    #pragma unroll
    for (int k = 1; k < KSPLIT; ++k) s += a[(size_t)k * n4 + i];
    reinterpret_cast<f32x4*>(out)[i] = s;
}

// h_out: out[m0+r][d] = sum_k A[m0+r][k] * Ht[d][k] — A row-major bf16 (round-5 proven).
__global__ __launch_bounds__(256) void k_gemm_bf16(const unsigned short* __restrict__ A,
                                                   const unsigned short* __restrict__ Ht,
                                                   float* __restrict__ out) {
    const int tid  = threadIdx.x;
    const int lane = tid & 63;
    const int wave = tid >> 6;
    const int r = lane & 15;
    const int g = lane >> 4;
    const int m0 = blockIdx.x * 16;
    const int t0 = blockIdx.y * NTB;
    const int kbeg = wave * (LN / 4);

    const f32x4 zero = {0.f, 0.f, 0.f, 0.f};
    f32x4 acc[NTB];
    #pragma unroll
    for (int t = 0; t < NTB; ++t) acc[t] = zero;

    bf16x8 Aa, Ab, Ba[NTB], Bb[NTB];
    const size_t arow = (size_t)(m0 + r) * LN;

    auto loadA = [&](bf16x8& av, int s) {
        int k = kbeg + s * 32 + g * 8;
        av = *reinterpret_cast<const bf16x8*>(A + arow + k);
    };
    auto loadB = [&](bf16x8 (&bb)[NTB], int s) {
        int k = kbeg + s * 32 + g * 8;
        #pragma unroll
        for (int t = 0; t < NTB; ++t)
            bb[t] = *reinterpret_cast<const bf16x8*>(Ht + (size_t)((t0 + t) * 16 + r) * LN + k);
    };
    auto proc = [&](bf16x8& av, bf16x8 (&bb)[NTB]) {
        #pragma unroll
        for (int t = 0; t < NTB; ++t)
            acc[t] = __builtin_amdgcn_mfma_f32_16x16x32_bf16(av, bb[t], acc[t], 0, 0, 0);
    };

    loadA(Aa, 0);
    loadB(Ba, 0);
    loadA(Ab, 1);
    #pragma unroll
    for (int s = 0; s < 32; s += 2) {
        loadB(Bb, s + 1);
        proc(Aa, Ba);
        if (s + 2 < 32) loadA(Aa, s + 2);
        if (s + 2 < 32) loadB(Ba, s + 2);
        proc(Ab, Bb);
        if (s + 3 < 32) loadA(Ab, s + 3);
    }

    __shared__ float buf[16 * NPADB];
    const int row4 = g * 4;
    for (int w4 = 0; w4 < 4; ++w4) {
        if (wave == w4) {
            #pragma unroll
            for (int t = 0; t < NTB; ++t) {
                #pragma unroll
                for (int q = 0; q < 4; ++q) {
                    int idx = (row4 + q) * NPADB + t * 16 + r;
                    if (w4 == 0) buf[idx] = acc[t][q];
                    else         buf[idx] += acc[t][q];
                }
            }
        }
        __syncthreads();
    }
    const int dbase = t0 * 16;
    for (int t2 = tid; t2 < 16 * NPADB; t2 += 256) {
        int row = t2 / NPADB, col = t2 % NPADB;
        int d = dbase + col;
        if (d < DN) out[(size_t)(m0 + row) * DN + d] = buf[row * NPADB + col];
    }
}

// h_in: pIn[by][m0+j][d] = sum_{i in 1024-window} Abf[i][m0+j] * Ht[d][i]
// Round-7-proven TR=1 staging skeleton, input switched fp32 adj -> bf16 Abf.
__global__ __launch_bounds__(256, 2) void k_gemm_t(const unsigned short* __restrict__ Abf,
                                                   const unsigned short* __restrict__ Ht,
                                                   float* __restrict__ pIn) {
    __shared__ unsigned short At[2][32 * 256];  // [j-row][256 i] bf16, XOR-swizzled, dbuf
    __shared__ float red[32][160];
    const int tid  = threadIdx.x;
    const int lane = tid & 63;
    const int wave = tid >> 6;
    const int r16  = lane & 15;
    const int g    = lane >> 4;
    const int m0 = blockIdx.x * 32;
    const int kq = blockIdx.y * KQ;

    f32x4 acc[2][NT];
    #pragma unroll
    for (int mt = 0; mt < 2; ++mt)
        #pragma unroll
        for (int n = 0; n < NT; ++n) acc[mt][n] = (f32x4){0.f, 0.f, 0.f, 0.f};

    unsigned int sv[16];  // each: 2 bf16 (j=jp*2, jp*2+1) for one i-row

    const int iof = tid >> 4;   // 16 i-rows per round
    const int jp  = tid & 15;
    auto stage_load = [&](int ss) {
        #pragma unroll
        for (int rr = 0; rr < 16; ++rr) {
            int il = rr * 16 + iof;
            sv[rr] = *reinterpret_cast<const unsigned int*>(
                Abf + (size_t)(kq + ss * 256 + il) * LN + m0 + jp * 2);
        }
    };
    auto stage_write = [&](int buf) {
        const int jA = jp * 2, jB = jA + 1;
        #pragma unroll
        for (int rr = 0; rr < 16; ++rr) {
            int k = rr * 16 + iof;
            At[buf][jA * 256 + (k ^ ((jA & 15) << 3))] = (unsigned short)(sv[rr] & 0xFFFFu);
            At[buf][jB * 256 + (k ^ ((jB & 15) << 3))] = (unsigned short)(sv[rr] >> 16);
        }
    };
    auto frag = [&](int buf, int mt, int s) {
        int row  = mt * 16 + r16;
        int kloc = wave * 64 + s * 32 + g * 8;
        return *reinterpret_cast<const bf16x8*>(&At[buf][row * 256 + (kloc ^ (r16 << 3))]);
    };
    auto loadB = [&](bf16x8 (&bb)[NT], int ss, int s) {
        int k = kq + ss * 256 + wave * 64 + s * 32 + g * 8;
        #pragma unroll
        for (int n = 0; n < NT; ++n)
            bb[n] = *reinterpret_cast<const bf16x8*>(Ht + (size_t)(n * 16 + r16) * LN + k);
    };

    stage_load(0);
    stage_write(0);
    __syncthreads();
    for (int ss = 0; ss < NSS; ++ss) {
        const int buf = ss & 1;
        if (ss + 1 < NSS) stage_load(ss + 1);
        #pragma unroll
        for (int s = 0; s < 2; ++s) {
            bf16x8 B[NT];
            loadB(B, ss, s);
            bf16x8 a0 = frag(buf, 0, s);
            bf16x8 a1 = frag(buf, 1, s);
            #pragma unroll
            for (int n = 0; n < NT; ++n) {
                acc[0][n] = __builtin_amdgcn_mfma_f32_16x16x32_bf16(a0, B[n], acc[0][n], 0, 0, 0);
                acc[1][n] = __builtin_amdgcn_mfma_f32_16x16x32_bf16(a1, B[n], acc[1][n], 0, 0, 0);
            }
        }
        __syncthreads();
        if (ss + 1 < NSS) stage_write(buf ^ 1);
        __syncthreads();
    }

    for (int w4 = 0; w4 < 4; ++w4) {
        if (wave == w4) {
            #pragma unroll
            for (int mt = 0; mt < 2; ++mt)
                #pragma unroll
                for (int n = 0; n < NT; ++n)
                    #pragma unroll
                    for (int q = 0; q < 4; ++q) {
                        int row = mt * 16 + g * 4 + q;
                        if (w4 == 0) red[row][n * 16 + r16]  = acc[mt][n][q];
                        else         red[row][n * 16 + r16] += acc[mt][n][q];
                    }
        }
        __syncthreads();
    }
    float* dst = pIn + (size_t)blockIdx.y * (LN * DN);
    for (int t2 = tid; t2 < 32 * DN; t2 += 256) {
        int row = t2 / DN, col = t2 % DN;
        dst[(size_t)(m0 + row) * DN + col] = red[row][col];
    }
}

// ---------------- fallback (small ws): legacy fp32 direct path ----------------
template <int TR>
__global__ __launch_bounds__(256, 2) void k_gemm(const float* __restrict__ adj,
                                                 const unsigned short* __restrict__ Ht,
                                                 float* __restrict__ out) {
    __shared__ unsigned short At[2][32 * 256];
    __shared__ float red[32][160];
    const int tid  = threadIdx.x;
    const int lane = tid & 63;
    const int wave = tid >> 6;
    const int r16  = lane & 15;
    const int g    = lane >> 4;
    const int m0 = blockIdx.x * 32;
    const int kq = blockIdx.y * KQ;
    f32x4 acc[2][NT];
    #pragma unroll
    for (int mt = 0; mt < 2; ++mt)
        #pragma unroll
        for (int n = 0; n < NT; ++n) acc[mt][n] = (f32x4){0.f, 0.f, 0.f, 0.f};
    f32x4 sv[16];
    auto stage_load = [&](int ss) {
        if (TR == 0) {
            const int row = tid >> 7;
            const int kk  = tid & 127;
            #pragma unroll
            for (int rr = 0; rr < 16; ++rr) {
                int rowr = rr * 2 + row;
                sv[rr] = *reinterpret_cast<const f32x4*>(
                    adj + ((size_t)(m0 + rowr) * LN + kq + ss * 256 + 2 * kk) * 2);
            }
        } else {
            const int iof2 = tid >> 4;
            const int jp2  = tid & 15;
            #pragma unroll
            for (int rr = 0; rr < 16; ++rr) {
                int il = rr * 16 + iof2;
                sv[rr] = *reinterpret_cast<const f32x4*>(
                    adj + ((size_t)(kq + ss * 256 + il) * LN + m0 + jp2 * 2) * 2);
            }
        }
    };
    auto stage_write = [&](int buf) {
        if (TR == 0) {
            const int row = tid >> 7;
            const int kk  = tid & 127;
            #pragma unroll
            for (int rr = 0; rr < 16; ++rr) {
                int rowr = rr * 2 + row;
                unsigned int u = f2bf(sv[rr].x + sv[rr].y) | (f2bf(sv[rr].z + sv[rr].w) << 16);
                *reinterpret_cast<unsigned int*>(
                    &At[buf][rowr * 256 + ((2 * kk) ^ ((rowr & 15) << 3))]) = u;
            }
        } else {
            const int iof2 = tid >> 4;
            const int jA = (tid & 15) * 2, jB = jA + 1;
            #pragma unroll
            for (int rr = 0; rr < 16; ++rr) {
                int k = rr * 16 + iof2;
                At[buf][jA * 256 + (k ^ ((jA & 15) << 3))] = (unsigned short)f2bf(sv[rr].x + sv[rr].y);
                At[buf][jB * 256 + (k ^ ((jB & 15) << 3))] = (unsigned short)f2bf(sv[rr].z + sv[rr].w);
            }
        }
    };
    auto frag = [&](int buf, int mt, int s) {
        int row  = mt * 16 + r16;
        int kloc = wave * 64 + s * 32 + g * 8;
        return *reinterpret_cast<const bf16x8*>(&At[buf][row * 256 + (kloc ^ (r16 << 3))]);
    };
    auto loadB = [&](bf16x8 (&bb)[NT], int ss, int s) {
        int k = kq + ss * 256 + wave * 64 + s * 32 + g * 8;
        #pragma unroll
        for (int n = 0; n < NT; ++n)
            bb[n] = *reinterpret_cast<const bf16x8*>(Ht + (size_t)(n * 16 + r16) * LN + k);
    };
    stage_load(0); stage_write(0); __syncthreads();
    for (int ss = 0; ss < NSS; ++ss) {
        const int buf = ss & 1;
        if (ss + 1 < NSS) stage_load(ss + 1);
        #pragma unroll
        for (int s = 0; s < 2; ++s) {
            bf16x8 B[NT];
            loadB(B, ss, s);
            bf16x8 a0 = frag(buf, 0, s);
            bf16x8 a1 = frag(buf, 1, s);
            #pragma unroll
            for (int n = 0; n < NT; ++n) {
                acc[0][n] = __builtin_amdgcn_mfma_f32_16x16x32_bf16(a0, B[n], acc[0][n], 0, 0, 0);
                acc[1][n] = __builtin_amdgcn_mfma_f32_16x16x32_bf16(a1, B[n], acc[1][n], 0, 0, 0);
            }
        }
        __syncthreads();
        if (ss + 1 < NSS) stage_write(buf ^ 1);
        __syncthreads();
    }
    for (int w4 = 0; w4 < 4; ++w4) {
        if (wave == w4) {
            #pragma unroll
            for (int mt = 0; mt < 2; ++mt)
                #pragma unroll
                for (int n = 0; n < NT; ++n)
                    #pragma unroll
                    for (int q = 0; q < 4; ++q) {
                        int row = mt * 16 + g * 4 + q;
                        if (w4 == 0) red[row][n * 16 + r16]  = acc[mt][n][q];
                        else         red[row][n * 16 + r16] += acc[mt][n][q];
                    }
        }
        __syncthreads();
    }
    for (int t2 = tid; t2 < 32 * DN; t2 += 256) {
        int row = t2 / DN, col = t2 % DN;
        atomicAdd(&out[(size_t)(m0 + row) * DN + col], red[row][col]);
    }
}

extern "C" void kernel_launch(void* const* d_in, const int* in_sizes, int n_in,
                              void* d_out, int out_size, void* d_ws, size_t ws_size,
                              hipStream_t stream) {
    const float* adj = (const float*)d_in[0];
    const float* h   = (const float*)d_in[1];
    float* out = (float*)d_out;
    char* ws = (char*)d_ws;

    unsigned short* Ht = (unsigned short*)ws;                      // 1.31 MB @ 0
    const size_t offAbf = 2u << 20;                                // bf16 A, 33.55 MB
    const size_t offPin = offAbf + (size_t)LN * LN * 2;            // h_in partials (4x)
    const size_t need   = offPin + (size_t)KSPLIT * LN * DN * 4;   // ~45.4 MB

    k_transpose<<<dim3(64, 5), 256, 0, stream>>>(h, Ht);

    if (ws_size >= need) {
        unsigned short* Abf = (unsigned short*)(ws + offAbf);
        float* pIn = (float*)(ws + offPin);
        k_conv<<<8192, 256, 0, stream>>>(adj, Abf);                                // pure stream
        k_gemm_bf16<<<dim3(256, 2), 256, 0, stream>>>(Abf, Ht, out + (size_t)LN * DN); // h_out
        k_gemm_t<<<dim3(128, KSPLIT), 256, 0, stream>>>(Abf, Ht, pIn);             // h_in partials
        const int n4 = (LN * DN) / 4;
        k_reduce_in<<<(n4 + 255) / 256, 256, 0, stream>>>(pIn, out, n4);
    } else {
        const int n4 = out_size / 4;
        k_zero<<<(n4 + 255) / 256, 256, 0, stream>>>((f32x4*)out, n4);
        k_gemm<0><<<dim3(128, KSPLIT), 256, 0, stream>>>(adj, Ht, out + (size_t)LN * DN);
        k_gemm<1><<<dim3(128, KSPLIT), 256, 0, stream>>>(adj, Ht, out);
    }
}